// Round 5
// baseline (162.661 us; speedup 1.0000x reference)
//
#include <hip/hip_runtime.h>
#include <cstdint>

#define LL 2048
#define HH 16
#define DD 64
#define NC 32
#define LSTR 1024
#define EPSF 1e-6f
#define PAD 72           // bf16 elems per LDS row = 36 dwords -> 2-way (free) b128 frags
#define IMGSZ 4608       // 64*72 ushorts = 9216 B per chunk image

typedef __bf16 bf16x8 __attribute__((ext_vector_type(8)));
typedef float floatx4 __attribute__((ext_vector_type(4)));
typedef unsigned short ushortx8 __attribute__((ext_vector_type(8)));
typedef unsigned short ushortx4 __attribute__((ext_vector_type(4)));
typedef unsigned short ushortx2 __attribute__((ext_vector_type(2)));

static __device__ __forceinline__ float fmap(float x){ return x > 0.f ? x + 1.f : __expf(x); }
static __device__ __forceinline__ unsigned short f2bf(float f){
    unsigned u = __builtin_bit_cast(unsigned, f);
    u += 0x7fffu + ((u >> 16) & 1u);
    return (unsigned short)(u >> 16);
}
static __device__ __forceinline__ float bf2f(unsigned short s){
    unsigned u = ((unsigned)s) << 16;
    return __builtin_bit_cast(float, u);
}
static __device__ __forceinline__ bf16x8 ldf(const unsigned short* p){
    return __builtin_bit_cast(bf16x8, *(const ushortx8*)p);
}
static __device__ __forceinline__ void gl_lds16(const unsigned short* g, unsigned short* l){
    __builtin_amdgcn_global_load_lds(
        (const __attribute__((address_space(1))) void*)g,
        (__attribute__((address_space(3))) void*)l, 16, 0, 0);
}

// ---- k1: per-chunk KVt[m][d] + Ksum + bf16 images (kf [s][d], v^T [m][s]) ----
__global__ __launch_bounds__(256) void k1(const float* __restrict__ kp, const float* __restrict__ vp,
                                          unsigned short* __restrict__ kvt, float* __restrict__ ks,
                                          unsigned short* __restrict__ kfimg, unsigned short* __restrict__ vtimg)
{
    __shared__ __align__(16) unsigned short kft[DD*PAD]; // kf^T [d][s]
    __shared__ __align__(16) unsigned short vtt[DD*PAD]; // v^T  [m][s]
    const int ci = blockIdx.x;
    const int c = ci & 31, bh = ci >> 5, b = bh >> 4, h = bh & 15;
    const int t = threadIdx.x;
    const int64_t gbase = ((int64_t)(b*LL + c*DD)*HH + h)*DD;
    unsigned short* kfi = kfimg + (int64_t)ci*IMGSZ;
#pragma unroll
    for (int i = 0; i < 2; ++i) {
        int flat = t + 256*i;                    // 512 items: 2 rows x 4 cols each
        int l0 = (flat >> 4) * 2, col = (flat & 15) << 2;
        const float* gk = kp + gbase + (int64_t)l0*LSTR + col;
        const float* gv = vp + gbase + (int64_t)l0*LSTR + col;
        float4 ka = *(const float4*)(gk);
        float4 kb = *(const float4*)(gk + LSTR);
        float4 va = *(const float4*)(gv);
        float4 vb = *(const float4*)(gv + LSTR);
        ushortx4 kra = { f2bf(fmap(ka.x)), f2bf(fmap(ka.y)), f2bf(fmap(ka.z)), f2bf(fmap(ka.w)) };
        ushortx4 krb = { f2bf(fmap(kb.x)), f2bf(fmap(kb.y)), f2bf(fmap(kb.z)), f2bf(fmap(kb.w)) };
        // row-major kf image for k3 (straight from registers)
        *(ushortx4*)(kfi + l0*PAD + col)     = kra;
        *(ushortx4*)(kfi + (l0+1)*PAD + col) = krb;
        float vaa[4] = {va.x,va.y,va.z,va.w}, vbb[4] = {vb.x,vb.y,vb.z,vb.w};
#pragma unroll
        for (int e = 0; e < 4; ++e) {
            *(ushortx2*)(kft + (col+e)*PAD + l0) = ushortx2{ kra[e], krb[e] };
            *(ushortx2*)(vtt + (col+e)*PAD + l0) = ushortx2{ f2bf(vaa[e]), f2bf(vbb[e]) };
        }
    }
    __syncthreads();
    // dump v^T image for k3 (flat, coalesced)
    unsigned short* vti = vtimg + (int64_t)ci*IMGSZ;
#pragma unroll
    for (int i = 0; i < 2; ++i) {
        int g = t + 256*i;                       // 512 of 576 ushort8 groups
        *(ushortx8*)(vti + g*8) = *(const ushortx8*)(vtt + g*8);
    }
    if (t < 64) *(ushortx8*)(vti + 4096 + t*8) = *(const ushortx8*)(vtt + 4096 + t*8);
    const int w = t >> 6, lane = t & 63, quad = lane >> 4, lr = lane & 15;
    const int m0 = 16*w;
    floatx4 acc[4];
#pragma unroll
    for (int dt = 0; dt < 4; ++dt) acc[dt] = floatx4{0.f,0.f,0.f,0.f};
#pragma unroll
    for (int kk = 0; kk < 2; ++kk) {
        bf16x8 a = ldf(vtt + (m0+lr)*PAD + kk*32 + quad*8);
#pragma unroll
        for (int dt = 0; dt < 4; ++dt) {
            bf16x8 bb = ldf(kft + (dt*16+lr)*PAD + kk*32 + quad*8);
            acc[dt] = __builtin_amdgcn_mfma_f32_16x16x32_bf16(a, bb, acc[dt], 0, 0, 0);
        }
    }
    unsigned short* kvo = kvt + (int64_t)ci*4096;   // [m][d]
#pragma unroll
    for (int dt = 0; dt < 4; ++dt)
#pragma unroll
        for (int r = 0; r < 4; ++r)
            kvo[(m0 + quad*4 + r)*DD + dt*16 + lr] = f2bf(acc[dt][r]);
    if (t < DD) {
        float s = 0.f;
#pragma unroll
        for (int j = 0; j < 8; ++j) {
            ushortx8 u = *(const ushortx8*)(kft + t*PAD + j*8);
#pragma unroll
            for (int e = 0; e < 8; ++e) s += bf2f(u[e]);
        }
        ks[(int64_t)ci*DD + t] = s;
    }
}

// ---- k2: exclusive prefix over chunks — all 32 loads independent, prefix in regs ----
__global__ __launch_bounds__(256) void k2(unsigned short* __restrict__ kvt, float* __restrict__ ks)
{
    const int blk = blockIdx.x;          // 512 = 64 bh * 8 parts
    const int bh = blk >> 3, part = blk & 7, t = threadIdx.x;
    unsigned short* base = kvt + (int64_t)bh*NC*4096 + (part*256 + t)*2;
    unsigned x[NC];
#pragma unroll
    for (int c = 0; c < NC; ++c) x[c] = *(const unsigned*)(base + (int64_t)c*4096);
    float r0 = 0.f, r1 = 0.f;
#pragma unroll
    for (int c = 0; c < NC; ++c) {
        unsigned o = (unsigned)f2bf(r0) | ((unsigned)f2bf(r1) << 16);
        r0 += bf2f((unsigned short)(x[c] & 0xffffu));
        r1 += bf2f((unsigned short)(x[c] >> 16));
        *(unsigned*)(base + (int64_t)c*4096) = o;
    }
    if (part == 0 && t < DD) {
        float kr[NC];
        float* kb = ks + (int64_t)bh*NC*DD + t;
#pragma unroll
        for (int c = 0; c < NC; ++c) kr[c] = kb[(int64_t)c*DD];
        float r = 0.f;
#pragma unroll
        for (int c = 0; c < NC; ++c) { kb[(int64_t)c*DD] = r; r += kr[c]; }
    }
}

// ---- k3: per-chunk output; kf/v^T tiles via async global_load_lds ----
__global__ __launch_bounds__(256, 4) void k3(const float* __restrict__ qp,
                                             const unsigned short* __restrict__ kfimg,
                                             const unsigned short* __restrict__ vtimg,
                                             const unsigned short* __restrict__ kvt,
                                             const float* __restrict__ ks, float* __restrict__ outp)
{
    __shared__ __align__(16) unsigned short qf [DD*PAD];  // [l][d]; wave-private after sync; scores overlay
    __shared__ __align__(16) unsigned short kfx[80*PAD];  // [s][d]; row64=Kprefix, 65-79=0
    __shared__ __align__(16) unsigned short vtt[DD*PAD];  // v^T [m][s]
    __shared__ float zr[DD];
    const int ci = blockIdx.x;
    const int c = ci & 31, bh = ci >> 5, b = bh >> 4, h = bh & 15;
    const int t = threadIdx.x;
    const int64_t gbase = ((int64_t)(b*LL + c*DD)*HH + h)*DD;
    const unsigned short* kvg = kvt + (int64_t)ci*4096;
    const float* ksg = ks + (int64_t)ci*DD;
    const int w = t >> 6, lane = t & 63, quad = lane >> 4, lr = lane & 15;

    // async global->LDS: 18 segments of 1024 B (9 kf image, 9 v^T image)
    {
        const unsigned short* kfi = kfimg + (int64_t)ci*IMGSZ;
        const unsigned short* vti = vtimg + (int64_t)ci*IMGSZ;
#pragma unroll
        for (int seg = 0; seg < 5; ++seg) {
            int s = w + seg*4;
            if (s < 18) {
                const unsigned short* src = (s < 9) ? (kfi + s*512) : (vti + (s-9)*512);
                unsigned short*       dst = (s < 9) ? (kfx + s*512) : (vtt + (s-9)*512);
                gl_lds16(src + lane*8, dst);
            }
        }
    }
    // stage qf (fp32 + fmap)
#pragma unroll
    for (int i = 0; i < 2; ++i) {
        int flat = t + 256*i;
        int l0 = (flat >> 4) * 2, col = (flat & 15) << 2;
        const float* gq = qp + gbase + (int64_t)l0*LSTR + col;
        float4 qa = *(const float4*)(gq);
        float4 qb = *(const float4*)(gq + LSTR);
        *(ushortx4*)(qf + l0*PAD + col)     = ushortx4{ f2bf(fmap(qa.x)), f2bf(fmap(qa.y)), f2bf(fmap(qa.z)), f2bf(fmap(qa.w)) };
        *(ushortx4*)(qf + (l0+1)*PAD + col) = ushortx4{ f2bf(fmap(qb.x)), f2bf(fmap(qb.y)), f2bf(fmap(qb.z)), f2bf(fmap(qb.w)) };
    }
    if (t < 135) *(ushortx8*)(kfx + 65*PAD + t*8) = ushortx8{0,0,0,0,0,0,0,0};
    if (t < DD)  kfx[64*PAD + t] = f2bf(ksg[t]);
    __syncthreads();   // drains vmcnt (incl. global_load_lds) + lds

    const int l0 = 16*w;
    bf16x8 aq[2];
    aq[0] = ldf(qf + (l0+lr)*PAD + quad*8);
    aq[1] = ldf(qf + (l0+lr)*PAD + 32 + quad*8);
    // S^T frags from global kv (L2/L3-resident), issued before GEMM1
    bf16x8 bs[2][4];
#pragma unroll
    for (int kk = 0; kk < 2; ++kk)
#pragma unroll
        for (int mt = 0; mt < 4; ++mt)
            bs[kk][mt] = ldf(kvg + (mt*16+lr)*DD + kk*32 + quad*8);

    // GEMM1: scores = qf * kf^T; tile 4 col0 = qf . Kprefix
    floatx4 sc[5];
#pragma unroll
    for (int tt = 0; tt < 5; ++tt) sc[tt] = floatx4{0.f,0.f,0.f,0.f};
#pragma unroll
    for (int kk = 0; kk < 2; ++kk)
#pragma unroll
        for (int tt = 0; tt < 5; ++tt) {
            bf16x8 bb = ldf(kfx + (tt*16+lr)*PAD + kk*32 + quad*8);
            sc[tt] = __builtin_amdgcn_mfma_f32_16x16x32_bf16(aq[kk], bb, sc[tt], 0, 0, 0);
        }

    // mask + z + overlay masked scores on own qf rows
    float zp[4] = {0.f,0.f,0.f,0.f};
#pragma unroll
    for (int tt = 0; tt < 4; ++tt)
#pragma unroll
        for (int r = 0; r < 4; ++r) {
            int row = l0 + quad*4 + r;
            int col = tt*16 + lr;
            float val = (col <= row) ? sc[tt][r] : 0.f;
            zp[r] += val;
            qf[row*PAD + col] = f2bf(val);
        }
#pragma unroll
    for (int r = 0; r < 4; ++r) zp[r] += (lr == 0) ? sc[4][r] : 0.f;
#pragma unroll
    for (int m = 1; m < 16; m <<= 1)
#pragma unroll
        for (int r = 0; r < 4; ++r) zp[r] += __shfl_xor(zp[r], m, 64);
    if (lr == 0)
#pragma unroll
        for (int r = 0; r < 4; ++r) zr[l0 + quad*4 + r] = 1.f / (zp[r] + EPSF);

    // GEMM2: out = Amask * v + qf * S
    floatx4 oa[4];
#pragma unroll
    for (int mt = 0; mt < 4; ++mt) oa[mt] = floatx4{0.f,0.f,0.f,0.f};
#pragma unroll
    for (int kk = 0; kk < 2; ++kk) {
        bf16x8 a2 = ldf(qf + (l0+lr)*PAD + kk*32 + quad*8);    // own rows (intra-wave RAW)
#pragma unroll
        for (int mt = 0; mt < 4; ++mt) {
            bf16x8 bv = ldf(vtt + (mt*16+lr)*PAD + kk*32 + quad*8);
            oa[mt] = __builtin_amdgcn_mfma_f32_16x16x32_bf16(a2, bv, oa[mt], 0, 0, 0);
        }
    }
#pragma unroll
    for (int kk = 0; kk < 2; ++kk)
#pragma unroll
        for (int mt = 0; mt < 4; ++mt)
            oa[mt] = __builtin_amdgcn_mfma_f32_16x16x32_bf16(aq[kk], bs[kk][mt], oa[mt], 0, 0, 0);
#pragma unroll
    for (int r = 0; r < 4; ++r) {
        int row = l0 + quad*4 + r;
        float rz = zr[row];
#pragma unroll
        for (int mt = 0; mt < 4; ++mt)
            outp[gbase + (int64_t)row*LSTR + mt*16 + lr] = oa[mt][r] * rz;
    }
}

extern "C" void kernel_launch(void* const* d_in, const int* in_sizes, int n_in,
                              void* d_out, int out_size, void* d_ws, size_t ws_size,
                              hipStream_t stream) {
    const float* q = (const float*)d_in[0];
    const float* k = (const float*)d_in[1];
    const float* v = (const float*)d_in[2];
    float* out = (float*)d_out;
    char* ws = (char*)d_ws;
    unsigned short* kvt   = (unsigned short*)ws;                          // 16 MiB
    float*          ks    = (float*)(ws + (size_t)2048*4096*2);           // 512 KiB
    unsigned short* kfimg = (unsigned short*)(ws + (size_t)17*1024*1024); // 18.9 MB
    unsigned short* vtimg = kfimg + (size_t)2048*IMGSZ;
    k1<<<2048, 256, 0, stream>>>(k, v, kvt, ks, kfimg, vtimg);
    k2<<<512,  256, 0, stream>>>(kvt, ks);
    k3<<<2048, 256, 0, stream>>>(q, kfimg, vtimg, kvt, ks, out);
}